// Round 11
// baseline (111.215 us; speedup 1.0000x reference)
//
#include <hip/hip_runtime.h>

// 5-layer MLP [B,64]->32->12->8->6->2, fp32.
// R10 skeleton (R6 DMA staging + swizzle, wave-private 8KB LDS dbuf, counted
// vmcnt) with (a) v_pk_fma_f32 math: weight pairs ride the scalar pipe
// (adjacent uniform scalar loads -> s_load_dwordx2 -> "s" asm operand),
// halving VALU issue; (b) NT=4, grid=1024 -> exactly 4 blocks/CU resident,
// single dispatch round.

typedef float v2f __attribute__((ext_vector_type(2)));
typedef __attribute__((address_space(3))) void* as3p;
typedef const __attribute__((address_space(1))) void* as1p;

#define BLOCK 256   // 4 waves/block
#define NT 4        // 64-row tiles per wave

// acc += w * x, packed 2xfp32; w = two adjacent uniform floats (SGPR pair).
__device__ __forceinline__ void pk_fma_w(v2f& acc, const float* __restrict__ Wp,
                                         v2f x) {
    v2f w;
    w[0] = Wp[0];   // uniform -> s_load (R10-proven scalar path)
    w[1] = Wp[1];   // adjacent -> merges into s_load_dwordx2 (even pair)
    asm("v_pk_fma_f32 %0, %1, %2, %0" : "+v"(acc) : "s"(w), "v"(x));
}

template <int IN, int OUT, bool RELU>
__device__ __forceinline__ void vlayer(const float* __restrict__ W,
                                       const float* __restrict__ b,
                                       const float* h_in, float* h_out) {
    v2f acc[OUT / 2];
#pragma unroll
    for (int o = 0; o < OUT / 2; ++o) {
        v2f a; a[0] = b[2 * o]; a[1] = b[2 * o + 1];
        acc[o] = a;
    }
#pragma unroll
    for (int i = 0; i < IN; ++i) {
        const float v = h_in[i];
        const v2f xv = {v, v};
#pragma unroll
        for (int o = 0; o < OUT / 2; ++o)
            pk_fma_w(acc[o], &W[i * OUT + 2 * o], xv);
    }
#pragma unroll
    for (int o = 0; o < OUT / 2; ++o) {
        h_out[2 * o]     = RELU ? fmaxf(acc[o][0], 0.0f) : acc[o][0];
        h_out[2 * o + 1] = RELU ? fmaxf(acc[o][1], 0.0f) : acc[o][1];
    }
}

__global__ __launch_bounds__(BLOCK, 4) void mlp_kernel(
        const float* __restrict__ x,
        const float* __restrict__ W0, const float* __restrict__ b0,
        const float* __restrict__ W1, const float* __restrict__ b1,
        const float* __restrict__ W2, const float* __restrict__ b2,
        const float* __restrict__ W3, const float* __restrict__ b3,
        const float* __restrict__ W4, const float* __restrict__ b4,
        float* __restrict__ out, int nrows) {
    extern __shared__ char lds[];
    const int t = threadIdx.x;
    const int wv = t >> 6;
    const int lane = t & 63;
    char* buf0 = lds + wv * 8192;
    char* buf1 = buf0 + 4096;

    const long long row0 = ((long long)blockIdx.x * 4 + wv) * (NT * 64);
    const char* xbase = reinterpret_cast<const char*>(x + row0 * 64);

    // --- R6-proven per-lane staging source offset (inverse of read swizzle).
    const int h = lane >> 3;
    const int q = (lane & 7) ^ h;
    const int stage_off = (2 * h + (q >> 2)) * 256 + (q & 3) * 16;

    // --- R6-proven per-lane LDS read offsets (row r = lane).
    const int R = lane >> 1;
    const int p2 = lane & 1;
    const int r7 = R & 7;
    int roff[4];
#pragma unroll
    for (int j = 0; j < 4; ++j)
        roff[j] = R * 128 + (((j + 4 * p2) ^ r7) << 4);

    // Stage global chunk gc (tile gc>>2, col-chunk gc&3) into buf.
    auto STAGE = [&](int gc, char* buf) {
        const char* s0 = xbase + (gc >> 2) * (64 * 256) + (gc & 3) * 64 +
                         stage_off;
#pragma unroll
        for (int k = 0; k < 4; ++k)
            __builtin_amdgcn_global_load_lds((as1p)(s0 + k * 4096),
                                             (as3p)(buf + k * 1024), 16, 0, 0);
    };

    STAGE(0, buf0);   // prologue

#pragma unroll 1
    for (int tt = 0; tt < NT; ++tt) {
        v2f acc[16];
#pragma unroll
        for (int o = 0; o < 16; ++o) {
            v2f a; a[0] = b0[2 * o]; a[1] = b0[2 * o + 1];
            acc[o] = a;
        }

#pragma unroll 1
        for (int c = 0; c < 4; ++c) {
            const int gc = tt * 4 + c;
            char* cur = (gc & 1) ? buf1 : buf0;
            char* oth = (gc & 1) ? buf0 : buf1;

            if (gc + 1 < NT * 4) {
                STAGE(gc + 1, oth);
                // 4 new loads in flight; drain only the current chunk's.
                asm volatile("s_waitcnt vmcnt(4)" ::: "memory");
            } else {
                asm volatile("s_waitcnt vmcnt(0)" ::: "memory");
            }
            __builtin_amdgcn_sched_barrier(0);

            // Conflict-free swizzled reads: 4x ds_read_b128 (16 floats).
            float xr[16];
#pragma unroll
            for (int j = 0; j < 4; ++j) {
                const float4 v =
                    *reinterpret_cast<const float4*>(cur + roff[j]);
                xr[4 * j + 0] = v.x; xr[4 * j + 1] = v.y;
                xr[4 * j + 2] = v.z; xr[4 * j + 3] = v.w;
            }

            // Layer-0 partial: 16 i-values x 16 packed outputs.
            const float* Wc = W0 + (c << 9);   // 16 rows * 32 cols
#pragma unroll
            for (int idx = 0; idx < 16; ++idx) {
                const float v = xr[idx];
                const v2f xv = {v, v};
#pragma unroll
                for (int o = 0; o < 16; ++o)
                    pk_fma_w(acc[o], &Wc[idx * 32 + 2 * o], xv);
            }
        }

        // ReLU on h0, unpack to scalar array for the tail.
        float h0[32];
#pragma unroll
        for (int o = 0; o < 16; ++o) {
            h0[2 * o]     = fmaxf(acc[o][0], 0.0f);
            h0[2 * o + 1] = fmaxf(acc[o][1], 0.0f);
        }

        // Tail layers (next tile's chunk-0 DMA flies during these).
        float h1[12], h2[8], h3[6], h4[2];
        vlayer<32, 12, true>(W1, b1, h0, h1);
        vlayer<12, 8, true>(W2, b2, h1, h2);
        vlayer<8, 6, true>(W3, b3, h2, h3);
        vlayer<6, 2, false>(W4, b4, h3, h4);

        reinterpret_cast<float2*>(out)[row0 + tt * 64 + lane] =
            make_float2(h4[0], h4[1]);
    }
}

extern "C" void kernel_launch(void* const* d_in, const int* in_sizes, int n_in,
                              void* d_out, int out_size, void* d_ws, size_t ws_size,
                              hipStream_t stream) {
    const float* x  = (const float*)d_in[0];
    const float* W0 = (const float*)d_in[1];
    const float* b0 = (const float*)d_in[2];
    const float* W1 = (const float*)d_in[3];
    const float* b1 = (const float*)d_in[4];
    const float* W2 = (const float*)d_in[5];
    const float* b2 = (const float*)d_in[6];
    const float* W3 = (const float*)d_in[7];
    const float* b3 = (const float*)d_in[8];
    const float* W4 = (const float*)d_in[9];
    const float* b4 = (const float*)d_in[10];
    float* out = (float*)d_out;

    const int nrows = in_sizes[0] / 64;                 // 1,048,576
    const int rows_per_block = 4 * NT * 64;             // 1024
    const int grid = nrows / rows_per_block;            // 1024 (exact)
    const size_t shmem = 4 * 8192;                      // 32 KiB/block

    mlp_kernel<<<grid, BLOCK, shmem, stream>>>(x, W0, b0, W1, b1, W2, b2,
                                               W3, b3, W4, b4, out, nrows);
}

// Round 12
// 64.931 us; speedup vs baseline: 1.7128x; 1.7128x over previous
//
#include <hip/hip_runtime.h>

// 5-layer MLP [B,64]->32->12->8->6->2, fp32 in/out.
// Layer 0 on matrix cores: v_mfma_f32_32x32x16_bf16, 3-pass truncated-bf16
// split (hi=trunc, lo=bf16(x-hi); D = Ah*Bh + Al*Bh + Ah*Bl) -> ~fp32 acc.
// Staging pipeline is R10-verbatim (global_load_lds DMA, R6 XOR swizzle,
// counted s_waitcnt vmcnt(4), wave-private LDS, no __syncthreads).
// D is transposed through an 8KB wave-private LDS buffer (unit-XOR swizzle,
// <=2 lanes/bank both directions); tail layers stay scalar fmaf (s_load
// weights, proven). BLOCK=64 (1 wave), 16KB LDS/wave -> 10 waves/CU.

typedef __attribute__((ext_vector_type(8))) short short8;
typedef __attribute__((ext_vector_type(16))) float f32x16;
typedef __attribute__((ext_vector_type(4))) unsigned uint4v;
typedef __attribute__((address_space(3))) void* as3p;
typedef const __attribute__((address_space(1))) void* as1p;

#define BLOCK 64
#define NT 4   // 64-row tiles per wave

__device__ __forceinline__ unsigned fbits(float x) {
    return __builtin_bit_cast(unsigned, x);
}
__device__ __forceinline__ float asf(unsigned u) {
    return __builtin_bit_cast(float, u);
}
// (hi16(ub)<<16) | hi16(ua)  -- one v_perm_b32
__device__ __forceinline__ unsigned packhi(unsigned ua, unsigned ub) {
    return __builtin_amdgcn_perm(ub, ua, 0x07060302u);
}
// 8 floats -> 8 truncated bf16 (element j = k-index j)
__device__ __forceinline__ short8 mk_hi(const float* f) {
    uint4v w;
#pragma unroll
    for (int t = 0; t < 4; ++t)
        w[t] = packhi(fbits(f[2 * t]), fbits(f[2 * t + 1]));
    return __builtin_bit_cast(short8, w);
}
// 8 floats -> bf16 of the truncation residuals
__device__ __forceinline__ short8 mk_lo(const float* f) {
    uint4v w;
#pragma unroll
    for (int t = 0; t < 4; ++t) {
        const float la = f[2 * t]     - asf(fbits(f[2 * t])     & 0xFFFF0000u);
        const float lb = f[2 * t + 1] - asf(fbits(f[2 * t + 1]) & 0xFFFF0000u);
        w[t] = packhi(fbits(la), fbits(lb));
    }
    return __builtin_bit_cast(short8, w);
}
#define MFMA(A, B, C) __builtin_amdgcn_mfma_f32_32x32x16_bf16(A, B, C, 0, 0, 0)

template <int IN, int OUT, bool RELU>
__device__ __forceinline__ void layer(const float* __restrict__ W,
                                      const float* __restrict__ b,
                                      const float* h_in, float* h_out) {
#pragma unroll
    for (int o = 0; o < OUT; ++o) h_out[o] = b[o];
#pragma unroll
    for (int i = 0; i < IN; ++i) {
        const float v = h_in[i];
#pragma unroll
        for (int o = 0; o < OUT; ++o)
            h_out[o] = fmaf(v, W[i * OUT + o], h_out[o]);   // uniform -> s_load
    }
    if (RELU) {
#pragma unroll
        for (int o = 0; o < OUT; ++o) h_out[o] = fmaxf(h_out[o], 0.0f);
    }
}

__global__ __launch_bounds__(BLOCK, 2) void mlp_kernel(
        const float* __restrict__ x,
        const float* __restrict__ W0, const float* __restrict__ b0,
        const float* __restrict__ W1, const float* __restrict__ b1,
        const float* __restrict__ W2, const float* __restrict__ b2,
        const float* __restrict__ W3, const float* __restrict__ b3,
        const float* __restrict__ W4, const float* __restrict__ b4,
        float* __restrict__ out, int nrows) {
    extern __shared__ char lds[];
    char* buf0 = lds;            // 4KB chunk buffer (even chunks)
    char* buf1 = lds + 4096;     // 4KB chunk buffer (odd chunks)
    char* h0b  = lds + 8192;     // 8KB h0 transpose buffer

    const int lane = threadIdx.x;          // 1 wave per block
    const long long row0 = (long long)blockIdx.x * (NT * 64);
    const char* xbase = reinterpret_cast<const char*>(x + row0 * 64);

    // --- R6/R10-proven per-lane staging source offset (inverse swizzle).
    const int hh = lane >> 3;
    const int qq = (lane & 7) ^ hh;
    const int stage_off = (2 * hh + (qq >> 2)) * 256 + (qq & 3) * 16;

    // --- A-fragment LDS read offsets: unit u of row r lives at slot
    //     (u + 4*(r&1)) ^ ((r>>1)&7) within super-row r>>1.
    const int r0 = lane & 31;        // A row (rt0); rt1 = r0+32
    const int hA = lane >> 5;        // k-half: k = 8*hA + j
    auto lds_off = [](int r, int u) {
        const int R = r >> 1, p = r & 1;
        return R * 128 + (((u + 4 * p) ^ (R & 7)) << 4);
    };
    const int aoff0 = lds_off(r0, 2 * hA);
    const int aoff1 = lds_off(r0, 2 * hA + 1);
    const int aoff2 = lds_off(r0 + 32, 2 * hA);
    const int aoff3 = lds_off(r0 + 32, 2 * hA + 1);

    // --- B fragments (W0), built once, held in registers. Lane holds
    //     B[k = c*16 + 8*hA + j][col = lane&31], j = 0..7.
    const int colB = lane & 31;
    short8 B0h, B0l, B1h, B1l, B2h, B2l, B3h, B3l;
    {
        float wf[8];
#define LOADB(c, BH, BL)                                                \
        {                                                               \
            _Pragma("unroll")                                           \
            for (int j = 0; j < 8; ++j)                                 \
                wf[j] = W0[((c) * 16 + 8 * hA + j) * 32 + colB];        \
            BH = mk_hi(wf);                                             \
            BL = mk_lo(wf);                                             \
        }
        LOADB(0, B0h, B0l)
        LOADB(1, B1h, B1l)
        LOADB(2, B2h, B2l)
        LOADB(3, B3h, B3l)
#undef LOADB
    }
    const float vb0 = b0[colB];   // bias for this lane's D column

    // Stage global chunk gc (tile gc>>2, col-chunk gc&3) into buf.
    auto STAGE = [&](int gc, char* buf) {
        const char* s0 = xbase + (gc >> 2) * (64 * 256) + (gc & 3) * 64 +
                         stage_off;
#pragma unroll
        for (int k = 0; k < 4; ++k)
            __builtin_amdgcn_global_load_lds((as1p)(s0 + k * 4096),
                                             (as3p)(buf + k * 1024), 16, 0, 0);
    };

    STAGE(0, buf0);   // prologue

#pragma unroll 1
    for (int tt = 0; tt < NT; ++tt) {
        f32x16 accA, accB;
#pragma unroll
        for (int r = 0; r < 16; ++r) { accA[r] = vb0; accB[r] = vb0; }

#define CHUNK_BODY(CUR, BH, BL)                                            \
        {                                                                  \
            float fA[8], fB[8];                                            \
            const float4 q0 = *reinterpret_cast<const float4*>(CUR + aoff0); \
            const float4 q1 = *reinterpret_cast<const float4*>(CUR + aoff1); \
            const float4 q2 = *reinterpret_cast<const float4*>(CUR + aoff2); \
            const float4 q3 = *reinterpret_cast<const float4*>(CUR + aoff3); \
            fA[0]=q0.x; fA[1]=q0.y; fA[2]=q0.z; fA[3]=q0.w;                \
            fA[4]=q1.x; fA[5]=q1.y; fA[6]=q1.z; fA[7]=q1.w;                \
            fB[0]=q2.x; fB[1]=q2.y; fB[2]=q2.z; fB[3]=q2.w;                \
            fB[4]=q3.x; fB[5]=q3.y; fB[6]=q3.z; fB[7]=q3.w;                \
            const short8 Ah = mk_hi(fA), Al = mk_lo(fA);                   \
            const short8 Ch = mk_hi(fB), Cl = mk_lo(fB);                   \
            accA = MFMA(Ah, BH, accA);                                     \
            accA = MFMA(Al, BH, accA);                                     \
            accA = MFMA(Ah, BL, accA);                                     \
            accB = MFMA(Ch, BH, accB);                                     \
            accB = MFMA(Cl, BH, accB);                                     \
            accB = MFMA(Ch, BL, accB);                                     \
        }
#define PHASE(c, BH, BL)                                                   \
        {                                                                  \
            const int gc = tt * 4 + (c);                                   \
            char* cur = ((c) & 1) ? buf1 : buf0;                           \
            char* oth = ((c) & 1) ? buf0 : buf1;                           \
            if (gc + 1 < NT * 4) {                                         \
                STAGE(gc + 1, oth);                                        \
                asm volatile("s_waitcnt vmcnt(4)" ::: "memory");           \
            } else {                                                       \
                asm volatile("s_waitcnt vmcnt(0)" ::: "memory");           \
            }                                                              \
            __builtin_amdgcn_sched_barrier(0);                             \
            CHUNK_BODY(cur, BH, BL)                                        \
        }

        PHASE(0, B0h, B0l)
        PHASE(1, B1h, B1l)
        PHASE(2, B2h, B2l)
        PHASE(3, B3h, B3l)
#undef PHASE
#undef CHUNK_BODY

        // --- ReLU + transpose D -> h0buf. D: col = lane&31,
        //     row = rt*32 + (reg&3) + 8*(reg>>2) + 4*(lane>>5).
        //     Col c of row r stored at unit (c>>2)^(r&7), word c&3.
#pragma unroll
        for (int reg = 0; reg < 16; ++reg) {
            const int r1 = (reg & 3) + 8 * (reg >> 2) + 4 * hA;   // rt0
            const int r2 = r1 + 32;                               // rt1
            const int w1 = r1 * 128 + (((colB >> 2) ^ (r1 & 7)) << 4) +
                           (colB & 3) * 4;
            const int w2 = r2 * 128 + (((colB >> 2) ^ (r2 & 7)) << 4) +
                           (colB & 3) * 4;
            *reinterpret_cast<float*>(h0b + w1) = fmaxf(accA[reg], 0.0f);
            *reinterpret_cast<float*>(h0b + w2) = fmaxf(accB[reg], 0.0f);
        }

        // Read own row back (8x ds_read_b128, swizzle-inverted).
        float xr[32];
#pragma unroll
        for (int u = 0; u < 8; ++u) {
            const int slot = u ^ (lane & 7);
            const float4 q = *reinterpret_cast<const float4*>(
                h0b + lane * 128 + slot * 16);
            xr[4 * u + 0] = q.x; xr[4 * u + 1] = q.y;
            xr[4 * u + 2] = q.z; xr[4 * u + 3] = q.w;
        }

        // Tail layers (next tile's chunk-0 DMA is in flight during these).
        float h1[12], h2[8], h3[6], h4[2];
        layer<32, 12, true>(W1, b1, xr, h1);
        layer<12, 8, true>(W2, b2, h1, h2);
        layer<8, 6, true>(W3, b3, h2, h3);
        layer<6, 2, false>(W4, b4, h3, h4);

        reinterpret_cast<float2*>(out)[row0 + tt * 64 + lane] =
            make_float2(h4[0], h4[1]);
    }
}

extern "C" void kernel_launch(void* const* d_in, const int* in_sizes, int n_in,
                              void* d_out, int out_size, void* d_ws, size_t ws_size,
                              hipStream_t stream) {
    const float* x  = (const float*)d_in[0];
    const float* W0 = (const float*)d_in[1];
    const float* b0 = (const float*)d_in[2];
    const float* W1 = (const float*)d_in[3];
    const float* b1 = (const float*)d_in[4];
    const float* W2 = (const float*)d_in[5];
    const float* b2 = (const float*)d_in[6];
    const float* W3 = (const float*)d_in[7];
    const float* b3 = (const float*)d_in[8];
    const float* W4 = (const float*)d_in[9];
    const float* b4 = (const float*)d_in[10];
    float* out = (float*)d_out;

    const int nrows = in_sizes[0] / 64;                 // 1,048,576
    const int rows_per_block = NT * 64;                 // 256
    const int grid = nrows / rows_per_block;            // 4096 (exact)
    const size_t shmem = 16384;                         // 8KB dbuf + 8KB h0

    mlp_kernel<<<grid, BLOCK, shmem, stream>>>(x, W0, b0, W1, b1, W2, b2,
                                               W3, b3, W4, b4, out, nrows);
}